// Round 3
// baseline (1304.237 us; speedup 1.0000x reference)
//
#include <hip/hip_runtime.h>

typedef unsigned short u16;
typedef unsigned int u32;
typedef __attribute__((ext_vector_type(4))) float f32x4;
typedef __attribute__((ext_vector_type(8))) short short8;
typedef __attribute__((ext_vector_type(4))) unsigned int u32x4;

#define DEV __device__ __forceinline__

DEV float bf2f(u16 u){ union{u32 i; float f;} x; x.i = ((u32)u)<<16; return x.f; }
DEV u16 f2bf(float f){ union{u32 i; float f;} x; x.f = f; u32 r = x.i + 0x7fffu + ((x.i>>16)&1u); return (u16)(r>>16); }

// =================== weight concat / transpose (fp32 in) ===================
// WcatTf [896][1024] fp32: rows 0-447 Wskew^T, 448-575 Wk^T, 576-703 Wv^T, 704-831 Wq^T, 832-847 Wbeta^T, 848-895 zero
// WoT [1024][128] bf16 = bf16(W_o^T)
__global__ __launch_bounds__(256) void concat_kernel(
    const float* __restrict__ Wskew, const float* __restrict__ Wk, const float* __restrict__ Wv,
    const float* __restrict__ Wq, const float* __restrict__ Wbeta, const float* __restrict__ Wo,
    float* __restrict__ WcatTf, u16* __restrict__ WoT)
{
  int idx = blockIdx.x*256 + threadIdx.x;
  if (idx < 896*1024){
    int n = idx >> 10, kk = idx & 1023;
    float v;
    if (n < 448)      v = Wskew[kk*448 + n];
    else if (n < 576) v = Wk[kk*128 + (n-448)];
    else if (n < 704) v = Wv[kk*128 + (n-576)];
    else if (n < 832) v = Wq[kk*128 + (n-704)];
    else if (n < 848) v = Wbeta[kk*16 + (n-832)];
    else              v = 0.f;
    WcatTf[idx] = v;
  } else {
    int r = idx - 896*1024;
    int n = r >> 7, kk = r & 127;
    WoT[r] = f2bf(Wo[kk*1024 + n]);
  }
}

// =================== split-bf16 MFMA GEMM: fp32 A/Bt -> fp32 C + epilogue ===================
// C = A*B, A[M][K] fp32 row-major, Bt[N][K] fp32 row-major. Split each input into
// hi+lo bf16 planes during LDS staging; C ~= Ah*Bh + Ah*Bl + Al*Bh (error ~2^-17).
// Epilogue: col<448 -> 0.5*tanh(v);  832<=col<848 -> sigmoid(v + bias[col-832]).
union U8 { u16 u[8]; short8 s; };

__global__ __launch_bounds__(256) void gemm_split_kernel(
    const float* __restrict__ A, const float* __restrict__ Bt, float* __restrict__ C,
    const float* __restrict__ bias, int M, int N, int K, int ldc)
{
  __shared__ u16 lAh[128*32]; __shared__ u16 lAl[128*32];
  __shared__ u16 lBh[128*32]; __shared__ u16 lBl[128*32];
  const int tid = threadIdx.x;
  const int wave = tid >> 6;
  const int lane = tid & 63;
  const int quad = lane >> 4, l15 = lane & 15;
  const int m0 = blockIdx.x * 128, n0 = blockIdx.y * 128;
  const int wm = (wave >> 1) * 64, wn = (wave & 1) * 64;
  const int srow = tid >> 1;            // 0..127
  const int scol = (tid & 1) * 16;      // 0 or 16
  const float* gA = A + (size_t)(m0 + srow)*K + scol;
  const float* gB = Bt + (size_t)(n0 + srow)*K + scol;

  f32x4 acc[4][4] = {};
  for (int kb = 0; kb < K; kb += 32){
    f32x4 av[4], bv[4];
    #pragma unroll
    for (int q=0;q<4;q++){ av[q] = *(const f32x4*)(gA + kb + 4*q); bv[q] = *(const f32x4*)(gB + kb + 4*q); }
    U8 ah[2], al[2], bh[2], bl[2];
    #pragma unroll
    for (int q=0;q<4;q++){
      #pragma unroll
      for (int e=0;e<4;e++){
        int t = 4*q + e;
        float fa = av[q][e];
        u16 h = f2bf(fa); ah[t>>3].u[t&7] = h; al[t>>3].u[t&7] = f2bf(fa - bf2f(h));
        float fb = bv[q][e];
        u16 g = f2bf(fb); bh[t>>3].u[t&7] = g; bl[t>>3].u[t&7] = f2bf(fb - bf2f(g));
      }
    }
    __syncthreads();                       // prior iteration's readers done
    *(short8*)&lAh[srow*32 + scol]     = ah[0].s;  *(short8*)&lAh[srow*32 + scol + 8] = ah[1].s;
    *(short8*)&lAl[srow*32 + scol]     = al[0].s;  *(short8*)&lAl[srow*32 + scol + 8] = al[1].s;
    *(short8*)&lBh[srow*32 + scol]     = bh[0].s;  *(short8*)&lBh[srow*32 + scol + 8] = bh[1].s;
    *(short8*)&lBl[srow*32 + scol]     = bl[0].s;  *(short8*)&lBl[srow*32 + scol + 8] = bl[1].s;
    __syncthreads();                       // stores visible
    short8 afh[4], afl[4], bfh[4], bfl[4];
    #pragma unroll
    for (int mi=0;mi<4;mi++){
      afh[mi] = *(const short8*)&lAh[(wm + mi*16 + l15)*32 + quad*8];
      afl[mi] = *(const short8*)&lAl[(wm + mi*16 + l15)*32 + quad*8];
    }
    #pragma unroll
    for (int ni=0;ni<4;ni++){
      bfh[ni] = *(const short8*)&lBh[(wn + ni*16 + l15)*32 + quad*8];
      bfl[ni] = *(const short8*)&lBl[(wn + ni*16 + l15)*32 + quad*8];
    }
    #pragma unroll
    for (int mi=0;mi<4;mi++)
      #pragma unroll
      for (int ni=0;ni<4;ni++){
        acc[mi][ni] = __builtin_amdgcn_mfma_f32_16x16x32_bf16(afh[mi], bfh[ni], acc[mi][ni], 0,0,0);
        acc[mi][ni] = __builtin_amdgcn_mfma_f32_16x16x32_bf16(afh[mi], bfl[ni], acc[mi][ni], 0,0,0);
        acc[mi][ni] = __builtin_amdgcn_mfma_f32_16x16x32_bf16(afl[mi], bfh[ni], acc[mi][ni], 0,0,0);
      }
  }
  #pragma unroll
  for (int mi=0;mi<4;mi++){
    #pragma unroll
    for (int ni=0;ni<4;ni++){
      const int col = n0 + wn + ni*16 + l15;
      const int rb_ = m0 + wm + mi*16 + quad*4;
      #pragma unroll
      for (int r=0;r<4;r++){
        float v = acc[mi][ni][r];
        const int row = rb_ + r;
        if (col < 448) v = 0.5f * tanhf(v);
        else if (col >= 832 && col < 848) v = 1.f/(1.f + expf(-(v + bias[col-832])));
        C[(size_t)row*ldc + col] = v;
      }
    }
  }
}

// =================== plain bf16 MFMA GEMM: bf16 A/Bt -> fp32 C ===================
__global__ __launch_bounds__(256) void gemm_bf16_kernel(
    const u16* __restrict__ A, const u16* __restrict__ Bt, float* __restrict__ C,
    int M, int N, int K, int ldc)
{
  __shared__ u16 ldsA[128*32];
  __shared__ u16 ldsB[128*32];
  const int tid = threadIdx.x;
  const int wave = tid >> 6;
  const int lane = tid & 63;
  const int quad = lane >> 4, l15 = lane & 15;
  const int m0 = blockIdx.x * 128, n0 = blockIdx.y * 128;
  const int wm = (wave >> 1) * 64, wn = (wave & 1) * 64;
  const int srow = tid >> 1;
  const int scol = (tid & 1) * 16;
  const u16* gA = A + (size_t)(m0 + srow)*K + scol;
  const u16* gB = Bt + (size_t)(n0 + srow)*K + scol;

  f32x4 acc[4][4] = {};
  for (int kb = 0; kb < K; kb += 32){
    short8 a0 = *(const short8*)(gA + kb);
    short8 a1 = *(const short8*)(gA + kb + 8);
    short8 b0 = *(const short8*)(gB + kb);
    short8 b1 = *(const short8*)(gB + kb + 8);
    __syncthreads();
    *(short8*)&ldsA[srow*32 + scol]     = a0;
    *(short8*)&ldsA[srow*32 + scol + 8] = a1;
    *(short8*)&ldsB[srow*32 + scol]     = b0;
    *(short8*)&ldsB[srow*32 + scol + 8] = b1;
    __syncthreads();
    short8 af[4], bf8[4];
    #pragma unroll
    for (int mi=0;mi<4;mi++) af[mi] = *(const short8*)&ldsA[(wm + mi*16 + l15)*32 + quad*8];
    #pragma unroll
    for (int ni=0;ni<4;ni++) bf8[ni] = *(const short8*)&ldsB[(wn + ni*16 + l15)*32 + quad*8];
    #pragma unroll
    for (int mi=0;mi<4;mi++)
      #pragma unroll
      for (int ni=0;ni<4;ni++)
        acc[mi][ni] = __builtin_amdgcn_mfma_f32_16x16x32_bf16(af[mi], bf8[ni], acc[mi][ni], 0,0,0);
  }
  #pragma unroll
  for (int mi=0;mi<4;mi++)
    #pragma unroll
    for (int ni=0;ni<4;ni++){
      const int col = n0 + wn + ni*16 + l15;
      const int rb_ = m0 + wm + mi*16 + quad*4;
      #pragma unroll
      for (int r=0;r<4;r++)
        C[(size_t)(rb_ + r)*ldc + col] = acc[mi][ni][r];
    }
}

// =================== expm of skew (2 lanes per matrix) ===================
__device__ constexpr int TRI_I[28] = {0,0,0,0,0,0,0, 1,1,1,1,1,1, 2,2,2,2,2, 3,3,3,3, 4,4,4, 5,5, 6};
__device__ constexpr int TRI_J[28] = {1,2,3,4,5,6,7, 2,3,4,5,6,7, 3,4,5,6,7, 4,5,6,7, 5,6,7, 6,7, 7};

DEV void pair_matmul(const float XA[4][4], const float XB[4][4], const float Mm[4][8], float Tm[4][8]){
  float Yo[4][8];
  #pragma unroll
  for (int r=0;r<4;r++)
    #pragma unroll
    for (int jj=0;jj<8;jj++) Yo[r][jj] = __shfl_xor(Mm[r][jj], 1);
  #pragma unroll
  for (int i=0;i<4;i++)
    #pragma unroll
    for (int jj=0;jj<8;jj++){
      float acc = 0.f;
      #pragma unroll
      for (int r=0;r<4;r++){ acc = fmaf(XA[i][r], Mm[r][jj], acc); acc = fmaf(XB[i][r], Yo[r][jj], acc); }
      Tm[i][jj] = acc;
    }
}

__global__ __launch_bounds__(256) void expm_kernel(const float* __restrict__ proj, float* __restrict__ O)
{
  const int tid = blockIdx.x*256 + threadIdx.x;
  const int pid = tid >> 1;     // matrix id [0, 262144)
  const int p = tid & 1;        // half: rows 4p..4p+3
  const int row = pid >> 4, h = pid & 15;
  const float* sk = proj + (size_t)row*896 + h*28;

  float Bm[4][8];
  #pragma unroll
  for (int i=0;i<4;i++)
    #pragma unroll
    for (int jj=0;jj<8;jj++) Bm[i][jj] = 0.f;
  #pragma unroll
  for (int c=0;c<28;c++){
    const int ti = TRI_I[c], tj = TRI_J[c];
    float v = sk[c] * 0.0625f;      // A/16 (scaling-and-squaring s=4)
    if (p==0){
      if (ti < 4) Bm[ti][tj] = v;
      if (tj < 4) Bm[tj][ti] = -v;
    } else {
      if (ti >= 4) Bm[ti-4][tj] = v;
      if (tj >= 4) Bm[tj-4][ti] = -v;
    }
  }
  float BA[4][4], BB[4][4];
  #pragma unroll
  for (int i=0;i<4;i++)
    #pragma unroll
    for (int r=0;r<4;r++){ float lo=Bm[i][r], hi=Bm[i][4+r]; BA[i][r] = p? hi: lo; BB[i][r] = p? lo: hi; }

  float Mm[4][8], Tm[4][8];
  #pragma unroll
  for (int i=0;i<4;i++)
    #pragma unroll
    for (int jj=0;jj<8;jj++) Mm[i][jj] = Bm[i][jj]*(1.f/6.f) + (((4*p+i)==jj)?1.f:0.f);
  const float coef[5] = {0.2f, 0.25f, 1.f/3.f, 0.5f, 1.f};
  #pragma unroll
  for (int st=0; st<5; st++){
    pair_matmul(BA, BB, Mm, Tm);
    #pragma unroll
    for (int i=0;i<4;i++)
      #pragma unroll
      for (int jj=0;jj<8;jj++) Mm[i][jj] = Tm[i][jj]*coef[st] + (((4*p+i)==jj)?1.f:0.f);
  }
  #pragma unroll
  for (int sq=0; sq<4; sq++){
    float MA[4][4], MB[4][4];
    #pragma unroll
    for (int i=0;i<4;i++)
      #pragma unroll
      for (int r=0;r<4;r++){ float lo=Mm[i][r], hi=Mm[i][4+r]; MA[i][r] = p? hi: lo; MB[i][r] = p? lo: hi; }
    pair_matmul(MA, MB, Mm, Tm);
    #pragma unroll
    for (int i=0;i<4;i++)
      #pragma unroll
      for (int jj=0;jj<8;jj++) Mm[i][jj] = Tm[i][jj];
  }
  const int b_ = row >> 12, t_ = row & 4095;
  const size_t obase = (((size_t)(b_*16 + h))*4096 + (size_t)t_)*64;
  #pragma unroll
  for (int i=0;i<4;i++){
    f32x4 lo = {Mm[i][0],Mm[i][1],Mm[i][2],Mm[i][3]};
    f32x4 hi = {Mm[i][4],Mm[i][5],Mm[i][6],Mm[i][7]};
    *(f32x4*)(O + obase + (size_t)(4*p+i)*8)     = lo;
    *(f32x4*)(O + obase + (size_t)(4*p+i)*8 + 4) = hi;
  }
}

// helpers: 8x8 matvec with 16 f32x4 regs
DEV void load16(const float* p, f32x4* M){
  #pragma unroll
  for (int q=0;q<16;q++) M[q] = *(const f32x4*)(p + 4*q);
}
DEV void rm_matvec8(const f32x4* M16, const float* x, float* res){
  #pragma unroll
  for (int i=0;i<8;i++){
    float acc = 0.f;
    #pragma unroll
    for (int a=0;a<8;a++) acc = fmaf(M16[2*i + (a>>2)][a&3], x[a], acc);
    res[i] = acc;
  }
}
DEV void cm_matvec8(const f32x4* M16, const float* x, float* res){
  #pragma unroll
  for (int i=0;i<8;i++){
    float acc = 0.f;
    #pragma unroll
    for (int a=0;a<8;a++) acc = fmaf(M16[2*a + (i>>2)][i&3], x[a], acc);
    res[i] = acc;
  }
}

// =================== C1: local prefix products within 64-step chunks ===================
__global__ __launch_bounds__(256) void chunkpfx_kernel(float* __restrict__ OR)
{
  int tid = blockIdx.x*256 + threadIdx.x;   // 32768 = 4096 tasks * 8 lanes
  int task = tid >> 3, j = tid & 7;
  int s = task >> 6, c = task & 63;
  float P[8], Pn[8];
  #pragma unroll
  for (int a=0;a<8;a++) P[a] = (a==j) ? 1.f : 0.f;
  float* base = OR + ((size_t)s*4096 + (size_t)c*64)*64;
  for (int tt=0; tt<64; tt++){
    float* slot = base + (size_t)tt*64;
    f32x4 Oc[16];
    load16(slot, Oc);              // O_t row-major
    rm_matvec8(Oc, P, Pn);         // P <- O_t * P
    #pragma unroll
    for (int a=0;a<8;a++) P[a] = Pn[a];
    f32x4 s0 = {P[0],P[1],P[2],P[3]}, s1 = {P[4],P[5],P[6],P[7]};
    *(f32x4*)(slot + j*8)     = s0;   // store col-major (same-wave: loads precede stores)
    *(f32x4*)(slot + j*8 + 4) = s1;
  }
}

// =================== C2: scan of chunk products -> Rbase_c ===================
__global__ __launch_bounds__(256) void chunkscan_kernel(const float* __restrict__ OR, float* __restrict__ Rbase)
{
  int tid = blockIdx.x*256 + threadIdx.x;   // 512 = 64 seqs * 8 lanes
  int s = tid >> 3, j = tid & 7;
  float Rb[8], Rn[8];
  #pragma unroll
  for (int a=0;a<8;a++) Rb[a] = (a==j) ? 1.f : 0.f;
  for (int c=0;c<64;c++){
    float* dst = Rbase + ((size_t)s*64 + c)*64 + j*8;
    f32x4 s0 = {Rb[0],Rb[1],Rb[2],Rb[3]}, s1 = {Rb[4],Rb[5],Rb[6],Rb[7]};
    *(f32x4*)(dst) = s0; *(f32x4*)(dst+4) = s1;     // col-major Rbase_c
    if (c < 63){
      const float* qs = OR + ((size_t)s*4096 + (size_t)(c*64+63))*64;  // Q_c col-major
      f32x4 Q[16];
      load16(qs, Q);
      cm_matvec8(Q, Rb, Rn);       // Rb <- Q_c * Rb
      #pragma unroll
      for (int a=0;a<8;a++) Rb[a] = Rn[a];
    }
  }
}

// =================== C3: compose R_t, normalize k, rotate k/v/q ===================
// scanin aliased into proj's dead skew slots: scanin(s,t) = proj + row*896 + h*28
__global__ __launch_bounds__(256) void rotate_kvq_kernel(float* __restrict__ OR, const float* __restrict__ Rbase,
    float* __restrict__ proj)
{
  int tid = blockIdx.x*256 + threadIdx.x;   // 262144
  int s = tid >> 12, t = tid & 4095;
  int c = t >> 6;
  int b = s >> 4, h = s & 15;
  int row = b*4096 + t;
  float* slot = OR + ((size_t)s*4096 + t)*64;
  f32x4 P4[16];
  load16(slot, P4);                          // P_c(t), col-major
  float* pr = proj + (size_t)row*896;
  float k[8], v[8], q[8];
  { f32x4 a = *(const f32x4*)(pr+448+h*8), b2 = *(const f32x4*)(pr+452+h*8);
    #pragma unroll
    for (int i=0;i<4;i++){ k[i]=a[i]; k[4+i]=b2[i]; } }
  { f32x4 a = *(const f32x4*)(pr+576+h*8), b2 = *(const f32x4*)(pr+580+h*8);
    #pragma unroll
    for (int i=0;i<4;i++){ v[i]=a[i]; v[4+i]=b2[i]; } }
  { f32x4 a = *(const f32x4*)(pr+704+h*8), b2 = *(const f32x4*)(pr+708+h*8);
    #pragma unroll
    for (int i=0;i<4;i++){ q[i]=a[i]; q[4+i]=b2[i]; } }
  float nn = 0.f;
  #pragma unroll
  for (int i=0;i<8;i++) nn = fmaf(k[i],k[i],nn);
  float inv = 1.f / fmaxf(sqrtf(nn), 1e-6f);
  #pragma unroll
  for (int i=0;i<8;i++) k[i] *= inv;

  const float* rb = Rbase + ((size_t)s*64 + c)*64;
  float kt[8], vt[8], qt[8];
  #pragma unroll
  for (int j=0;j<8;j++){
    float rbv[8];
    { f32x4 a = *(const f32x4*)(rb + j*8), b2 = *(const f32x4*)(rb + j*8 + 4);
      #pragma unroll
      for (int i=0;i<4;i++){ rbv[i]=a[i]; rbv[4+i]=b2[i]; } }
    float Rc[8];
    cm_matvec8(P4, rbv, Rc);        // column j of R_t = P * Rbase[:,j]
    f32x4 s0 = {Rc[0],Rc[1],Rc[2],Rc[3]}, s1 = {Rc[4],Rc[5],Rc[6],Rc[7]};
    *(f32x4*)(slot + j*8) = s0; *(f32x4*)(slot + j*8 + 4) = s1;   // R_t col-major (in place)
    float a0=0.f, a1=0.f, a2=0.f;
    #pragma unroll
    for (int i=0;i<8;i++){ a0 = fmaf(Rc[i],k[i],a0); a1 = fmaf(Rc[i],v[i],a1); a2 = fmaf(Rc[i],q[i],a2); }
    kt[j]=a0; vt[j]=a1; qt[j]=a2;
  }
  float beta = pr[832+h];
  float qk = 0.f;
  #pragma unroll
  for (int j=0;j<8;j++) qk = fmaf(kt[j], qt[j], qk);
  float* sip = pr + h*28;     // dead skew slot of this (row,h); writes <448, reads >=448
  f32x4 w0={kt[0],kt[1],kt[2],kt[3]}, w1={kt[4],kt[5],kt[6],kt[7]};
  f32x4 w2={vt[0],vt[1],vt[2],vt[3]}, w3={vt[4],vt[5],vt[6],vt[7]};
  f32x4 w4={qt[0],qt[1],qt[2],qt[3]}, w5={qt[4],qt[5],qt[6],qt[7]};
  f32x4 w6={beta, qk, 0.f, 0.f};
  *(f32x4*)(sip)=w0; *(f32x4*)(sip+4)=w1; *(f32x4*)(sip+8)=w2; *(f32x4*)(sip+12)=w3;
  *(f32x4*)(sip+16)=w4; *(f32x4*)(sip+20)=w5; *(f32x4*)(sip+24)=w6;
}

// =================== D: the serial delta scan (rotation-free) ===================
struct SG { f32x4 k0[4], k1[4], q0[4], q1[4], m[4]; float v[4]; };

DEV void load_group(SG& g, const float* base, int j){
  #pragma unroll
  for (int u=0;u<4;u++){
    const float* p = base + (size_t)u*896;
    g.k0[u] = *(const f32x4*)(p);
    g.k1[u] = *(const f32x4*)(p+4);
    g.q0[u] = *(const f32x4*)(p+16);
    g.q1[u] = *(const f32x4*)(p+20);
    g.m[u]  = *(const f32x4*)(p+24);   // [beta, qk, -, -]
    g.v[u]  = p[8+j];
  }
}

DEV void do_step(const SG& g, int u, float* d, float* op, int t){
  float kd, qd;
  { const f32x4 a = g.k0[u], b2 = g.k1[u];
    kd = ((a[0]*d[0] + a[1]*d[1]) + (a[2]*d[2] + a[3]*d[3]))
       + ((b2[0]*d[4] + b2[1]*d[5]) + (b2[2]*d[6] + b2[3]*d[7])); }
  { const f32x4 a = g.q0[u], b2 = g.q1[u];
    qd = ((a[0]*d[0] + a[1]*d[1]) + (a[2]*d[2] + a[3]*d[3]))
       + ((b2[0]*d[4] + b2[1]*d[5]) + (b2[2]*d[6] + b2[3]*d[7])); }
  float w = g.m[u][0] * (g.v[u] - kd);
  #pragma unroll
  for (int i=0;i<4;i++) d[i]   = fmaf(g.k0[u][i], w, d[i]);
  #pragma unroll
  for (int i=0;i<4;i++) d[4+i] = fmaf(g.k1[u][i], w, d[4+i]);
  op[(size_t)t*8] = fmaf(g.m[u][1], w, qd);    // o~ = q.d_old + (q.k)*w
}

__global__ __launch_bounds__(64) void scan_kernel(const float* __restrict__ proj, float* __restrict__ oo)
{
  int lane = threadIdx.x;
  int g = lane >> 3, j = lane & 7;
  int s = blockIdx.x*8 + g;
  int b = s >> 4, h = s & 15;
  const float* si = proj + (size_t)b*4096*896 + h*28;   // stride 896 per t
  float* op = oo + (size_t)s*4096*8 + j;
  float d[8];
  #pragma unroll
  for (int i=0;i<8;i++) d[i]=0.f;
  SG A_, B_;
  load_group(A_, si, j);
  for (int t0=0; t0<4096; t0+=8){
    load_group(B_, si + (size_t)(t0+4)*896, j);
    do_step(A_,0,d,op,t0);   do_step(A_,1,d,op,t0+1);
    do_step(A_,2,d,op,t0+2); do_step(A_,3,d,op,t0+3);
    int tn = (t0+8 < 4096) ? t0+8 : 4088;               // clamp: last prefetch unused
    load_group(A_, si + (size_t)tn*896, j);
    do_step(B_,0,d,op,t0+4); do_step(B_,1,d,op,t0+5);
    do_step(B_,2,d,op,t0+6); do_step(B_,3,d,op,t0+7);
  }
}

// =================== E: rotate outputs back: o = R_t * o~, write bf16 for out-GEMM ===================
__global__ __launch_bounds__(256) void rotout_kernel(const float* __restrict__ OR, const float* __restrict__ oo,
                                                     u16* __restrict__ obf)
{
  int tid = blockIdx.x*256 + threadIdx.x;   // 262144
  int s = tid >> 12, t = tid & 4095;
  int b = s >> 4, h = s & 15;
  int row = b*4096 + t;
  const float* slot = OR + ((size_t)s*4096 + t)*64;
  f32x4 R4[16];
  load16(slot, R4);
  float u[8];
  { const float* up = oo + ((size_t)s*4096 + t)*8;
    f32x4 a = *(const f32x4*)(up), b2 = *(const f32x4*)(up+4);
    #pragma unroll
    for (int i=0;i<4;i++){ u[i]=a[i]; u[4+i]=b2[i]; } }
  float o[8];
  cm_matvec8(R4, u, o);
  u32 p0 = (u32)f2bf(o[0]) | ((u32)f2bf(o[1])<<16);
  u32 p1 = (u32)f2bf(o[2]) | ((u32)f2bf(o[3])<<16);
  u32 p2 = (u32)f2bf(o[4]) | ((u32)f2bf(o[5])<<16);
  u32 p3 = (u32)f2bf(o[6]) | ((u32)f2bf(o[7])<<16);
  u32x4 pk = {p0,p1,p2,p3};
  *(u32x4*)(void*)(obf + (size_t)row*128 + h*8) = pk;
}

// =================== launch ===================
extern "C" void kernel_launch(void* const* d_in, const int* in_sizes, int n_in,
                              void* d_out, int out_size, void* d_ws, size_t ws_size,
                              hipStream_t stream)
{
  const float* x     = (const float*)d_in[0];
  const float* Wskew = (const float*)d_in[1];
  const float* Wk    = (const float*)d_in[2];
  const float* Wv    = (const float*)d_in[3];
  const float* Wq    = (const float*)d_in[4];
  const float* Wbeta = (const float*)d_in[5];
  const float* bbeta = (const float*)d_in[6];
  const float* Wo    = (const float*)d_in[7];

  char* w = (char*)d_ws; size_t off = 0;
  auto alloc = [&](size_t bytes)->void*{ void* p = w + off; off += (bytes + 255) & ~(size_t)255; return p; };
  float* WcatTf = (float*)alloc((size_t)896*1024*4);
  u16*   WoT    = (u16*)  alloc((size_t)1024*128*2);
  float* proj   = (float*)alloc((size_t)16384*896*4);
  float* OR     = (float*)alloc((size_t)262144*64*4);
  float* Rbase  = (float*)alloc((size_t)64*64*64*4);
  float* oo     = (float*)alloc((size_t)262144*8*4);
  u16*   obf    = (u16*)proj;   // proj fully dead after scan_kernel; 4MB << 56MB

  hipLaunchKernelGGL(concat_kernel, dim3(4096), dim3(256), 0, stream,
                     Wskew, Wk, Wv, Wq, Wbeta, Wo, WcatTf, WoT);
  hipLaunchKernelGGL(gemm_split_kernel, dim3(128,7), dim3(256), 0, stream,
                     x, WcatTf, proj, bbeta, 16384, 896, 1024, 896);
  hipLaunchKernelGGL(expm_kernel, dim3(2048), dim3(256), 0, stream, proj, OR);
  hipLaunchKernelGGL(chunkpfx_kernel, dim3(128), dim3(256), 0, stream, OR);
  hipLaunchKernelGGL(chunkscan_kernel, dim3(2), dim3(256), 0, stream, OR, Rbase);
  hipLaunchKernelGGL(rotate_kvq_kernel, dim3(1024), dim3(256), 0, stream, OR, Rbase, proj);
  hipLaunchKernelGGL(scan_kernel, dim3(8), dim3(64), 0, stream, proj, oo);
  hipLaunchKernelGGL(rotout_kernel, dim3(1024), dim3(256), 0, stream, OR, oo, obf);
  hipLaunchKernelGGL(gemm_bf16_kernel, dim3(128,8), dim3(256), 0, stream,
                     obf, WoT, (float*)d_out, 16384, 1024, 128, 1024);
}

// Round 4
// 575.936 us; speedup vs baseline: 2.2646x; 2.2646x over previous
//
#include <hip/hip_runtime.h>

typedef unsigned short u16;
typedef unsigned int u32;
typedef __attribute__((ext_vector_type(4))) float f32x4;
typedef __attribute__((ext_vector_type(8))) short short8;
typedef __attribute__((ext_vector_type(4))) unsigned int u32x4;

#define DEV __device__ __forceinline__

DEV float bf2f(u16 u){ union{u32 i; float f;} x; x.i = ((u32)u)<<16; return x.f; }
DEV u16 f2bf(float f){ union{u32 i; float f;} x; x.f = f; u32 r = x.i + 0x7fffu + ((x.i>>16)&1u); return (u16)(r>>16); }

// =================== weight concat / transpose (fp32 in) ===================
__global__ __launch_bounds__(256) void concat_kernel(
    const float* __restrict__ Wskew, const float* __restrict__ Wk, const float* __restrict__ Wv,
    const float* __restrict__ Wq, const float* __restrict__ Wbeta, const float* __restrict__ Wo,
    float* __restrict__ WcatTf, u16* __restrict__ WoT)
{
  int idx = blockIdx.x*256 + threadIdx.x;
  if (idx < 896*1024){
    int n = idx >> 10, kk = idx & 1023;
    float v;
    if (n < 448)      v = Wskew[kk*448 + n];
    else if (n < 576) v = Wk[kk*128 + (n-448)];
    else if (n < 704) v = Wv[kk*128 + (n-576)];
    else if (n < 832) v = Wq[kk*128 + (n-704)];
    else if (n < 848) v = Wbeta[kk*16 + (n-832)];
    else              v = 0.f;
    WcatTf[idx] = v;
  } else {
    int r = idx - 896*1024;
    int n = r >> 7, kk = r & 127;
    WoT[r] = f2bf(Wo[kk*1024 + n]);
  }
}

// =================== split-bf16 MFMA GEMM: fp32 A/Bt -> fp32 C + epilogue ===================
union U8 { u16 u[8]; short8 s; };

__global__ __launch_bounds__(256) void gemm_split_kernel(
    const float* __restrict__ A, const float* __restrict__ Bt, float* __restrict__ C,
    const float* __restrict__ bias, int M, int N, int K, int ldc)
{
  __shared__ u16 lAh[128*32]; __shared__ u16 lAl[128*32];
  __shared__ u16 lBh[128*32]; __shared__ u16 lBl[128*32];
  const int tid = threadIdx.x;
  const int wave = tid >> 6;
  const int lane = tid & 63;
  const int quad = lane >> 4, l15 = lane & 15;
  const int m0 = blockIdx.x * 128, n0 = blockIdx.y * 128;
  const int wm = (wave >> 1) * 64, wn = (wave & 1) * 64;
  const int srow = tid >> 1;            // 0..127
  const int scol = (tid & 1) * 16;      // 0 or 16
  const float* gA = A + (size_t)(m0 + srow)*K + scol;
  const float* gB = Bt + (size_t)(n0 + srow)*K + scol;

  f32x4 acc[4][4] = {};
  for (int kb = 0; kb < K; kb += 32){
    f32x4 av[4], bv[4];
    #pragma unroll
    for (int q=0;q<4;q++){ av[q] = *(const f32x4*)(gA + kb + 4*q); bv[q] = *(const f32x4*)(gB + kb + 4*q); }
    U8 ah[2], al[2], bh[2], bl[2];
    #pragma unroll
    for (int q=0;q<4;q++){
      #pragma unroll
      for (int e=0;e<4;e++){
        int t = 4*q + e;
        float fa = av[q][e];
        u16 h = f2bf(fa); ah[t>>3].u[t&7] = h; al[t>>3].u[t&7] = f2bf(fa - bf2f(h));
        float fb = bv[q][e];
        u16 g = f2bf(fb); bh[t>>3].u[t&7] = g; bl[t>>3].u[t&7] = f2bf(fb - bf2f(g));
      }
    }
    __syncthreads();
    *(short8*)&lAh[srow*32 + scol]     = ah[0].s;  *(short8*)&lAh[srow*32 + scol + 8] = ah[1].s;
    *(short8*)&lAl[srow*32 + scol]     = al[0].s;  *(short8*)&lAl[srow*32 + scol + 8] = al[1].s;
    *(short8*)&lBh[srow*32 + scol]     = bh[0].s;  *(short8*)&lBh[srow*32 + scol + 8] = bh[1].s;
    *(short8*)&lBl[srow*32 + scol]     = bl[0].s;  *(short8*)&lBl[srow*32 + scol + 8] = bl[1].s;
    __syncthreads();
    short8 afh[4], afl[4], bfh[4], bfl[4];
    #pragma unroll
    for (int mi=0;mi<4;mi++){
      afh[mi] = *(const short8*)&lAh[(wm + mi*16 + l15)*32 + quad*8];
      afl[mi] = *(const short8*)&lAl[(wm + mi*16 + l15)*32 + quad*8];
    }
    #pragma unroll
    for (int ni=0;ni<4;ni++){
      bfh[ni] = *(const short8*)&lBh[(wn + ni*16 + l15)*32 + quad*8];
      bfl[ni] = *(const short8*)&lBl[(wn + ni*16 + l15)*32 + quad*8];
    }
    #pragma unroll
    for (int mi=0;mi<4;mi++)
      #pragma unroll
      for (int ni=0;ni<4;ni++){
        acc[mi][ni] = __builtin_amdgcn_mfma_f32_16x16x32_bf16(afh[mi], bfh[ni], acc[mi][ni], 0,0,0);
        acc[mi][ni] = __builtin_amdgcn_mfma_f32_16x16x32_bf16(afh[mi], bfl[ni], acc[mi][ni], 0,0,0);
        acc[mi][ni] = __builtin_amdgcn_mfma_f32_16x16x32_bf16(afl[mi], bfh[ni], acc[mi][ni], 0,0,0);
      }
  }
  #pragma unroll
  for (int mi=0;mi<4;mi++){
    #pragma unroll
    for (int ni=0;ni<4;ni++){
      const int col = n0 + wn + ni*16 + l15;
      const int rb_ = m0 + wm + mi*16 + quad*4;
      #pragma unroll
      for (int r=0;r<4;r++){
        float v = acc[mi][ni][r];
        const int row = rb_ + r;
        if (col < 448) v = 0.5f * tanhf(v);
        else if (col >= 832 && col < 848) v = 1.f/(1.f + expf(-(v + bias[col-832])));
        C[(size_t)row*ldc + col] = v;
      }
    }
  }
}

// =================== plain bf16 MFMA GEMM: bf16 A/Bt -> fp32 C ===================
__global__ __launch_bounds__(256) void gemm_bf16_kernel(
    const u16* __restrict__ A, const u16* __restrict__ Bt, float* __restrict__ C,
    int M, int N, int K, int ldc)
{
  __shared__ u16 ldsA[128*32];
  __shared__ u16 ldsB[128*32];
  const int tid = threadIdx.x;
  const int wave = tid >> 6;
  const int lane = tid & 63;
  const int quad = lane >> 4, l15 = lane & 15;
  const int m0 = blockIdx.x * 128, n0 = blockIdx.y * 128;
  const int wm = (wave >> 1) * 64, wn = (wave & 1) * 64;
  const int srow = tid >> 1;
  const int scol = (tid & 1) * 16;
  const u16* gA = A + (size_t)(m0 + srow)*K + scol;
  const u16* gB = Bt + (size_t)(n0 + srow)*K + scol;

  f32x4 acc[4][4] = {};
  for (int kb = 0; kb < K; kb += 32){
    short8 a0 = *(const short8*)(gA + kb);
    short8 a1 = *(const short8*)(gA + kb + 8);
    short8 b0 = *(const short8*)(gB + kb);
    short8 b1 = *(const short8*)(gB + kb + 8);
    __syncthreads();
    *(short8*)&ldsA[srow*32 + scol]     = a0;
    *(short8*)&ldsA[srow*32 + scol + 8] = a1;
    *(short8*)&ldsB[srow*32 + scol]     = b0;
    *(short8*)&ldsB[srow*32 + scol + 8] = b1;
    __syncthreads();
    short8 af[4], bf8[4];
    #pragma unroll
    for (int mi=0;mi<4;mi++) af[mi] = *(const short8*)&ldsA[(wm + mi*16 + l15)*32 + quad*8];
    #pragma unroll
    for (int ni=0;ni<4;ni++) bf8[ni] = *(const short8*)&ldsB[(wn + ni*16 + l15)*32 + quad*8];
    #pragma unroll
    for (int mi=0;mi<4;mi++)
      #pragma unroll
      for (int ni=0;ni<4;ni++)
        acc[mi][ni] = __builtin_amdgcn_mfma_f32_16x16x32_bf16(af[mi], bf8[ni], acc[mi][ni], 0,0,0);
  }
  #pragma unroll
  for (int mi=0;mi<4;mi++)
    #pragma unroll
    for (int ni=0;ni<4;ni++){
      const int col = n0 + wn + ni*16 + l15;
      const int rb_ = m0 + wm + mi*16 + quad*4;
      #pragma unroll
      for (int r=0;r<4;r++)
        C[(size_t)(rb_ + r)*ldc + col] = acc[mi][ni][r];
    }
}

// =================== expm of skew (2 lanes per matrix) ===================
__device__ constexpr int TRI_I[28] = {0,0,0,0,0,0,0, 1,1,1,1,1,1, 2,2,2,2,2, 3,3,3,3, 4,4,4, 5,5, 6};
__device__ constexpr int TRI_J[28] = {1,2,3,4,5,6,7, 2,3,4,5,6,7, 3,4,5,6,7, 4,5,6,7, 5,6,7, 6,7, 7};

DEV void pair_matmul(const float XA[4][4], const float XB[4][4], const float Mm[4][8], float Tm[4][8]){
  float Yo[4][8];
  #pragma unroll
  for (int r=0;r<4;r++)
    #pragma unroll
    for (int jj=0;jj<8;jj++) Yo[r][jj] = __shfl_xor(Mm[r][jj], 1);
  #pragma unroll
  for (int i=0;i<4;i++)
    #pragma unroll
    for (int jj=0;jj<8;jj++){
      float acc = 0.f;
      #pragma unroll
      for (int r=0;r<4;r++){ acc = fmaf(XA[i][r], Mm[r][jj], acc); acc = fmaf(XB[i][r], Yo[r][jj], acc); }
      Tm[i][jj] = acc;
    }
}

__global__ __launch_bounds__(256) void expm_kernel(const float* __restrict__ proj, float* __restrict__ O)
{
  const int tid = blockIdx.x*256 + threadIdx.x;
  const int pid = tid >> 1;     // matrix id [0, 262144)
  const int p = tid & 1;        // half: rows 4p..4p+3
  const int row = pid >> 4, h = pid & 15;
  const float* sk = proj + (size_t)row*896 + h*28;

  float Bm[4][8];
  #pragma unroll
  for (int i=0;i<4;i++)
    #pragma unroll
    for (int jj=0;jj<8;jj++) Bm[i][jj] = 0.f;
  #pragma unroll
  for (int c=0;c<28;c++){
    const int ti = TRI_I[c], tj = TRI_J[c];
    float v = sk[c] * 0.0625f;      // A/16 (scaling-and-squaring s=4)
    if (p==0){
      if (ti < 4) Bm[ti][tj] = v;
      if (tj < 4) Bm[tj][ti] = -v;
    } else {
      if (ti >= 4) Bm[ti-4][tj] = v;
      if (tj >= 4) Bm[tj-4][ti] = -v;
    }
  }
  float BA[4][4], BB[4][4];
  #pragma unroll
  for (int i=0;i<4;i++)
    #pragma unroll
    for (int r=0;r<4;r++){ float lo=Bm[i][r], hi=Bm[i][4+r]; BA[i][r] = p? hi: lo; BB[i][r] = p? lo: hi; }

  float Mm[4][8], Tm[4][8];
  #pragma unroll
  for (int i=0;i<4;i++)
    #pragma unroll
    for (int jj=0;jj<8;jj++) Mm[i][jj] = Bm[i][jj]*(1.f/6.f) + (((4*p+i)==jj)?1.f:0.f);
  const float coef[5] = {0.2f, 0.25f, 1.f/3.f, 0.5f, 1.f};
  #pragma unroll
  for (int st=0; st<5; st++){
    pair_matmul(BA, BB, Mm, Tm);
    #pragma unroll
    for (int i=0;i<4;i++)
      #pragma unroll
      for (int jj=0;jj<8;jj++) Mm[i][jj] = Tm[i][jj]*coef[st] + (((4*p+i)==jj)?1.f:0.f);
  }
  #pragma unroll
  for (int sq=0; sq<4; sq++){
    float MA[4][4], MB[4][4];
    #pragma unroll
    for (int i=0;i<4;i++)
      #pragma unroll
      for (int r=0;r<4;r++){ float lo=Mm[i][r], hi=Mm[i][4+r]; MA[i][r] = p? hi: lo; MB[i][r] = p? lo: hi; }
    pair_matmul(MA, MB, Mm, Tm);
    #pragma unroll
    for (int i=0;i<4;i++)
      #pragma unroll
      for (int jj=0;jj<8;jj++) Mm[i][jj] = Tm[i][jj];
  }
  const int b_ = row >> 12, t_ = row & 4095;
  const size_t obase = (((size_t)(b_*16 + h))*4096 + (size_t)t_)*64;
  #pragma unroll
  for (int i=0;i<4;i++){
    f32x4 lo = {Mm[i][0],Mm[i][1],Mm[i][2],Mm[i][3]};
    f32x4 hi = {Mm[i][4],Mm[i][5],Mm[i][6],Mm[i][7]};
    *(f32x4*)(O + obase + (size_t)(4*p+i)*8)     = lo;
    *(f32x4*)(O + obase + (size_t)(4*p+i)*8 + 4) = hi;
  }
}

// helpers: 8x8 matvec with 16 f32x4 regs
DEV void load16(const float* p, f32x4* M){
  #pragma unroll
  for (int q=0;q<16;q++) M[q] = *(const f32x4*)(p + 4*q);
}
DEV void rm_matvec8(const f32x4* M16, const float* x, float* res){
  #pragma unroll
  for (int i=0;i<8;i++){
    float acc = 0.f;
    #pragma unroll
    for (int a=0;a<8;a++) acc = fmaf(M16[2*i + (a>>2)][a&3], x[a], acc);
    res[i] = acc;
  }
}
DEV void cm_matvec8(const f32x4* M16, const float* x, float* res){
  #pragma unroll
  for (int i=0;i<8;i++){
    float acc = 0.f;
    #pragma unroll
    for (int a=0;a<8;a++) acc = fmaf(M16[2*a + (i>>2)][i&3], x[a], acc);
    res[i] = acc;
  }
}

// =================== C1: local prefix products within 64-step chunks ===================
__global__ __launch_bounds__(256) void chunkpfx_kernel(float* __restrict__ OR)
{
  int tid = blockIdx.x*256 + threadIdx.x;   // 32768 = 4096 tasks * 8 lanes
  int task = tid >> 3, j = tid & 7;
  int s = task >> 6, c = task & 63;
  float P[8], Pn[8];
  #pragma unroll
  for (int a=0;a<8;a++) P[a] = (a==j) ? 1.f : 0.f;
  float* base = OR + ((size_t)s*4096 + (size_t)c*64)*64;
  for (int tt=0; tt<64; tt++){
    float* slot = base + (size_t)tt*64;
    f32x4 Oc[16];
    load16(slot, Oc);              // O_t row-major
    rm_matvec8(Oc, P, Pn);         // P <- O_t * P
    #pragma unroll
    for (int a=0;a<8;a++) P[a] = Pn[a];
    f32x4 s0 = {P[0],P[1],P[2],P[3]}, s1 = {P[4],P[5],P[6],P[7]};
    *(f32x4*)(slot + j*8)     = s0;   // store col-major (same-wave: loads precede stores)
    *(f32x4*)(slot + j*8 + 4) = s1;
  }
}

// =================== C2: scan of chunk products -> Rbase_c ===================
__global__ __launch_bounds__(256) void chunkscan_kernel(const float* __restrict__ OR, float* __restrict__ Rbase)
{
  int tid = blockIdx.x*256 + threadIdx.x;   // 512 = 64 seqs * 8 lanes
  int s = tid >> 3, j = tid & 7;
  float Rb[8], Rn[8];
  #pragma unroll
  for (int a=0;a<8;a++) Rb[a] = (a==j) ? 1.f : 0.f;
  for (int c=0;c<64;c++){
    float* dst = Rbase + ((size_t)s*64 + c)*64 + j*8;
    f32x4 s0 = {Rb[0],Rb[1],Rb[2],Rb[3]}, s1 = {Rb[4],Rb[5],Rb[6],Rb[7]};
    *(f32x4*)(dst) = s0; *(f32x4*)(dst+4) = s1;     // col-major Rbase_c
    if (c < 63){
      const float* qs = OR + ((size_t)s*4096 + (size_t)(c*64+63))*64;  // Q_c col-major
      f32x4 Q[16];
      load16(qs, Q);
      cm_matvec8(Q, Rb, Rn);       // Rb <- Q_c * Rb
      #pragma unroll
      for (int a=0;a<8;a++) Rb[a] = Rn[a];
    }
  }
}

// =================== C3: compose R_t, normalize k, rotate k/v/q ===================
// scanin aliased into proj's dead skew slots: scanin(s,t) = proj + row*896 + h*28
__global__ __launch_bounds__(256) void rotate_kvq_kernel(float* __restrict__ OR, const float* __restrict__ Rbase,
    float* __restrict__ proj)
{
  int tid = blockIdx.x*256 + threadIdx.x;   // 262144
  int s = tid >> 12, t = tid & 4095;
  int c = t >> 6;
  int b = s >> 4, h = s & 15;
  int row = b*4096 + t;
  float* slot = OR + ((size_t)s*4096 + t)*64;
  f32x4 P4[16];
  load16(slot, P4);                          // P_c(t), col-major
  float* pr = proj + (size_t)row*896;
  float k[8], v[8], q[8];
  { f32x4 a = *(const f32x4*)(pr+448+h*8), b2 = *(const f32x4*)(pr+452+h*8);
    #pragma unroll
    for (int i=0;i<4;i++){ k[i]=a[i]; k[4+i]=b2[i]; } }
  { f32x4 a = *(const f32x4*)(pr+576+h*8), b2 = *(const f32x4*)(pr+580+h*8);
    #pragma unroll
    for (int i=0;i<4;i++){ v[i]=a[i]; v[4+i]=b2[i]; } }
  { f32x4 a = *(const f32x4*)(pr+704+h*8), b2 = *(const f32x4*)(pr+708+h*8);
    #pragma unroll
    for (int i=0;i<4;i++){ q[i]=a[i]; q[4+i]=b2[i]; } }
  float nn = 0.f;
  #pragma unroll
  for (int i=0;i<8;i++) nn = fmaf(k[i],k[i],nn);
  float inv = 1.f / fmaxf(sqrtf(nn), 1e-6f);
  #pragma unroll
  for (int i=0;i<8;i++) k[i] *= inv;

  const float* rb = Rbase + ((size_t)s*64 + c)*64;
  float kt[8], vt[8], qt[8];
  #pragma unroll
  for (int j=0;j<8;j++){
    float rbv[8];
    { f32x4 a = *(const f32x4*)(rb + j*8), b2 = *(const f32x4*)(rb + j*8 + 4);
      #pragma unroll
      for (int i=0;i<4;i++){ rbv[i]=a[i]; rbv[4+i]=b2[i]; } }
    float Rc[8];
    cm_matvec8(P4, rbv, Rc);        // column j of R_t = P * Rbase[:,j]
    f32x4 s0 = {Rc[0],Rc[1],Rc[2],Rc[3]}, s1 = {Rc[4],Rc[5],Rc[6],Rc[7]};
    *(f32x4*)(slot + j*8) = s0; *(f32x4*)(slot + j*8 + 4) = s1;   // R_t col-major (in place)
    float a0=0.f, a1=0.f, a2=0.f;
    #pragma unroll
    for (int i=0;i<8;i++){ a0 = fmaf(Rc[i],k[i],a0); a1 = fmaf(Rc[i],v[i],a1); a2 = fmaf(Rc[i],q[i],a2); }
    kt[j]=a0; vt[j]=a1; qt[j]=a2;
  }
  float beta = pr[832+h];
  float qk = 0.f;
  #pragma unroll
  for (int j=0;j<8;j++) qk = fmaf(kt[j], qt[j], qk);
  float* sip = pr + h*28;     // dead skew slot of this (row,h); writes <448, reads >=448
  f32x4 w0={kt[0],kt[1],kt[2],kt[3]}, w1={kt[4],kt[5],kt[6],kt[7]};
  f32x4 w2={vt[0],vt[1],vt[2],vt[3]}, w3={vt[4],vt[5],vt[6],vt[7]};
  f32x4 w4={qt[0],qt[1],qt[2],qt[3]}, w5={qt[4],qt[5],qt[6],qt[7]};
  f32x4 w6={beta, qk, 0.f, 0.f};
  *(f32x4*)(sip)=w0; *(f32x4*)(sip+4)=w1; *(f32x4*)(sip+8)=w2; *(f32x4*)(sip+12)=w3;
  *(f32x4*)(sip+16)=w4; *(f32x4*)(sip+20)=w5; *(f32x4*)(sip+24)=w6;
}

// =================== D: chunk-parallel delta scan ===================
// Record at proj + (b*4096+t)*896 + h*28: [0..7]=k~, [8..15]=v~, [16..23]=q~, [24]=beta, [25]=q~.k~
// d_t = A_t d_{t-1} + u_t, A_t = I - beta k k^T (8x8), columns independent.

// Pass 1: per (s, chunk, col j): M_c[:,j] (product of A_t) and w_c[:,j] (zero-init run).
__global__ __launch_bounds__(256) void scan_pass1_kernel(const float* __restrict__ proj,
    float* __restrict__ Mbuf, float* __restrict__ wbuf)
{
  int tid = blockIdx.x*256 + threadIdx.x;   // 32768 = 4096 tasks * 8 lanes
  int task = tid >> 3, j = tid & 7;         // task = s*64 + c
  int s = task >> 6, c = task & 63;
  int b = s >> 4, h = s & 15;
  const float* rec = proj + ((size_t)b*4096 + (size_t)c*64)*896 + h*28;
  float m[8], w[8];
  #pragma unroll
  for (int i=0;i<8;i++){ m[i] = (i==j)?1.f:0.f; w[i] = 0.f; }
  for (int tt=0; tt<64; tt++){
    const float* p = rec + (size_t)tt*896;
    f32x4 k0 = *(const f32x4*)(p), k1 = *(const f32x4*)(p+4);
    float vt = p[8+j];
    float beta = p[24];
    float s1, s2;
    s1 = ((k0[0]*m[0] + k0[1]*m[1]) + (k0[2]*m[2] + k0[3]*m[3]))
       + ((k1[0]*m[4] + k1[1]*m[5]) + (k1[2]*m[6] + k1[3]*m[7]));
    s2 = ((k0[0]*w[0] + k0[1]*w[1]) + (k0[2]*w[2] + k0[3]*w[3]))
       + ((k1[0]*w[4] + k1[1]*w[5]) + (k1[2]*w[6] + k1[3]*w[7]));
    float c1 = -beta*s1, c2 = beta*(vt - s2);
    #pragma unroll
    for (int i=0;i<4;i++){ m[i] = fmaf(k0[i], c1, m[i]); m[4+i] = fmaf(k1[i], c1, m[4+i]); }
    #pragma unroll
    for (int i=0;i<4;i++){ w[i] = fmaf(k0[i], c2, w[i]); w[4+i] = fmaf(k1[i], c2, w[4+i]); }
  }
  float* md = Mbuf + (size_t)task*64 + j*8;
  float* wd = wbuf + (size_t)task*64 + j*8;
  f32x4 m0={m[0],m[1],m[2],m[3]}, m1={m[4],m[5],m[6],m[7]};
  f32x4 w0={w[0],w[1],w[2],w[3]}, w1={w[4],w[5],w[6],w[7]};
  *(f32x4*)(md) = m0; *(f32x4*)(md+4) = m1;
  *(f32x4*)(wd) = w0; *(f32x4*)(wd+4) = w1;
}

// Mid: sequential over 64 chunks; store exclusive-prefix d_start(c).
__global__ __launch_bounds__(64) void scan_mid_kernel(const float* __restrict__ Mbuf,
    const float* __restrict__ wbuf, float* __restrict__ dstart)
{
  int tid = blockIdx.x*64 + threadIdx.x;    // 512 = 64 seqs * 8 lanes
  int s = tid >> 3, j = tid & 7;
  float d[8];
  #pragma unroll
  for (int i=0;i<8;i++) d[i] = 0.f;
  // prefetch chunk 0
  size_t base = (size_t)s*64*64;
  f32x4 M[16]; load16(Mbuf + base, M);
  f32x4 wv0 = *(const f32x4*)(wbuf + base + j*8), wv1 = *(const f32x4*)(wbuf + base + j*8 + 4);
  for (int c=0; c<64; c++){
    float* dd = dstart + base + (size_t)c*64 + j*8;
    f32x4 s0 = {d[0],d[1],d[2],d[3]}, s1 = {d[4],d[5],d[6],d[7]};
    *(f32x4*)(dd) = s0; *(f32x4*)(dd+4) = s1;
    float dn[8];
    cm_matvec8(M, d, dn);
    #pragma unroll
    for (int i=0;i<4;i++){ d[i] = dn[i] + wv0[i]; d[4+i] = dn[4+i] + wv1[i]; }
    if (c < 63){
      size_t nb = base + (size_t)(c+1)*64;
      load16(Mbuf + nb, M);
      wv0 = *(const f32x4*)(wbuf + nb + j*8); wv1 = *(const f32x4*)(wbuf + nb + j*8 + 4);
    }
  }
}

// Pass 2: re-run chunk from d_start, emit outputs o~_t[j] = q~ . d_t[:,j].
__global__ __launch_bounds__(256) void scan_pass2_kernel(const float* __restrict__ proj,
    const float* __restrict__ dstart, float* __restrict__ oo)
{
  int tid = blockIdx.x*256 + threadIdx.x;   // 32768
  int task = tid >> 3, j = tid & 7;
  int s = task >> 6, c = task & 63;
  int b = s >> 4, h = s & 15;
  const float* rec = proj + ((size_t)b*4096 + (size_t)c*64)*896 + h*28;
  float* op = oo + (((size_t)s*4096 + (size_t)c*64)*8) + j;
  float d[8];
  { const float* ds = dstart + (size_t)task*64 + j*8;
    f32x4 a = *(const f32x4*)(ds), b2 = *(const f32x4*)(ds+4);
    #pragma unroll
    for (int i=0;i<4;i++){ d[i]=a[i]; d[4+i]=b2[i]; } }
  for (int tt=0; tt<64; tt++){
    const float* p = rec + (size_t)tt*896;
    f32x4 k0 = *(const f32x4*)(p),    k1 = *(const f32x4*)(p+4);
    f32x4 q0 = *(const f32x4*)(p+16), q1 = *(const f32x4*)(p+20);
    f32x4 mb = *(const f32x4*)(p+24);           // [beta, qk, -, -]
    float vt = p[8+j];
    float kd, qd;
    kd = ((k0[0]*d[0] + k0[1]*d[1]) + (k0[2]*d[2] + k0[3]*d[3]))
       + ((k1[0]*d[4] + k1[1]*d[5]) + (k1[2]*d[6] + k1[3]*d[7]));
    qd = ((q0[0]*d[0] + q0[1]*d[1]) + (q0[2]*d[2] + q0[3]*d[3]))
       + ((q1[0]*d[4] + q1[1]*d[5]) + (q1[2]*d[6] + q1[3]*d[7]));
    float w_ = mb[0] * (vt - kd);
    #pragma unroll
    for (int i=0;i<4;i++){ d[i] = fmaf(k0[i], w_, d[i]); d[4+i] = fmaf(k1[i], w_, d[4+i]); }
    op[(size_t)tt*8] = fmaf(mb[1], w_, qd);
  }
}

// =================== E: rotate outputs back: o = R_t * o~, write bf16 for out-GEMM ===================
__global__ __launch_bounds__(256) void rotout_kernel(const float* __restrict__ OR, const float* __restrict__ oo,
                                                     u16* __restrict__ obf)
{
  int tid = blockIdx.x*256 + threadIdx.x;   // 262144
  int s = tid >> 12, t = tid & 4095;
  int b = s >> 4, h = s & 15;
  int row = b*4096 + t;
  const float* slot = OR + ((size_t)s*4096 + t)*64;
  f32x4 R4[16];
  load16(slot, R4);
  float u[8];
  { const float* up = oo + ((size_t)s*4096 + t)*8;
    f32x4 a = *(const f32x4*)(up), b2 = *(const f32x4*)(up+4);
    #pragma unroll
    for (int i=0;i<4;i++){ u[i]=a[i]; u[4+i]=b2[i]; } }
  float o[8];
  cm_matvec8(R4, u, o);
  u32 p0 = (u32)f2bf(o[0]) | ((u32)f2bf(o[1])<<16);
  u32 p1 = (u32)f2bf(o[2]) | ((u32)f2bf(o[3])<<16);
  u32 p2 = (u32)f2bf(o[4]) | ((u32)f2bf(o[5])<<16);
  u32 p3 = (u32)f2bf(o[6]) | ((u32)f2bf(o[7])<<16);
  u32x4 pk = {p0,p1,p2,p3};
  *(u32x4*)(void*)(obf + (size_t)row*128 + h*8) = pk;
}

// =================== launch ===================
extern "C" void kernel_launch(void* const* d_in, const int* in_sizes, int n_in,
                              void* d_out, int out_size, void* d_ws, size_t ws_size,
                              hipStream_t stream)
{
  const float* x     = (const float*)d_in[0];
  const float* Wskew = (const float*)d_in[1];
  const float* Wk    = (const float*)d_in[2];
  const float* Wv    = (const float*)d_in[3];
  const float* Wq    = (const float*)d_in[4];
  const float* Wbeta = (const float*)d_in[5];
  const float* bbeta = (const float*)d_in[6];
  const float* Wo    = (const float*)d_in[7];

  char* w = (char*)d_ws; size_t off = 0;
  auto alloc = [&](size_t bytes)->void*{ void* p = w + off; off += (bytes + 255) & ~(size_t)255; return p; };
  float* WcatTf = (float*)alloc((size_t)896*1024*4);
  u16*   WoT    = (u16*)  alloc((size_t)1024*128*2);
  float* proj   = (float*)alloc((size_t)16384*896*4);
  float* OR     = (float*)alloc((size_t)262144*64*4);
  float* Rbase  = (float*)alloc((size_t)64*64*64*4);
  float* oo     = (float*)alloc((size_t)262144*8*4);
  float* Mbuf   = (float*)alloc((size_t)4096*64*4);
  float* wbuf   = (float*)alloc((size_t)4096*64*4);
  float* dstart = (float*)alloc((size_t)4096*64*4);
  u16*   obf    = (u16*)proj;   // proj fully dead after scan pass2; 4MB << 56MB

  hipLaunchKernelGGL(concat_kernel, dim3(4096), dim3(256), 0, stream,
                     Wskew, Wk, Wv, Wq, Wbeta, Wo, WcatTf, WoT);
  hipLaunchKernelGGL(gemm_split_kernel, dim3(128,7), dim3(256), 0, stream,
                     x, WcatTf, proj, bbeta, 16384, 896, 1024, 896);
  hipLaunchKernelGGL(expm_kernel, dim3(2048), dim3(256), 0, stream, proj, OR);
  hipLaunchKernelGGL(chunkpfx_kernel, dim3(128), dim3(256), 0, stream, OR);
  hipLaunchKernelGGL(chunkscan_kernel, dim3(2), dim3(256), 0, stream, OR, Rbase);
  hipLaunchKernelGGL(rotate_kvq_kernel, dim3(1024), dim3(256), 0, stream, OR, Rbase, proj);
  hipLaunchKernelGGL(scan_pass1_kernel, dim3(128), dim3(256), 0, stream, proj, Mbuf, wbuf);
  hipLaunchKernelGGL(scan_mid_kernel, dim3(8), dim3(64), 0, stream, Mbuf, wbuf, dstart);
  hipLaunchKernelGGL(scan_pass2_kernel, dim3(128), dim3(256), 0, stream, proj, dstart, oo);
  hipLaunchKernelGGL(rotout_kernel, dim3(1024), dim3(256), 0, stream, OR, oo, obf);
  hipLaunchKernelGGL(gemm_bf16_kernel, dim3(128,8), dim3(256), 0, stream,
                     obf, WoT, (float*)d_out, 16384, 1024, 128, 1024);
}

// Round 5
// 566.217 us; speedup vs baseline: 2.3034x; 1.0172x over previous
//
#include <hip/hip_runtime.h>

typedef unsigned short u16;
typedef unsigned int u32;
typedef __attribute__((ext_vector_type(4))) float f32x4;
typedef __attribute__((ext_vector_type(8))) short short8;
typedef __attribute__((ext_vector_type(4))) unsigned int u32x4;

#define DEV __device__ __forceinline__

DEV float bf2f(u16 u){ union{u32 i; float f;} x; x.i = ((u32)u)<<16; return x.f; }
DEV u16 f2bf(float f){ union{u32 i; float f;} x; x.f = f; u32 r = x.i + 0x7fffu + ((x.i>>16)&1u); return (u16)(r>>16); }

union U8 { u16 u[8]; short8 s; };

// =================== split x into hi/lo bf16 planes ===================
__global__ __launch_bounds__(256) void splitx_kernel(const float* __restrict__ x,
    u16* __restrict__ xh, u16* __restrict__ xl)
{
  size_t base = ((size_t)blockIdx.x*256 + threadIdx.x) * 8;   // 16384*1024/8 threads
  f32x4 a = *(const f32x4*)(x + base), b = *(const f32x4*)(x + base + 4);
  U8 h, l;
  #pragma unroll
  for (int e=0;e<4;e++){
    u16 hh = f2bf(a[e]); h.u[e]   = hh; l.u[e]   = f2bf(a[e] - bf2f(hh));
    u16 gg = f2bf(b[e]); h.u[4+e] = gg; l.u[4+e] = f2bf(b[e] - bf2f(gg));
  }
  *(short8*)(xh + base) = h.s;
  *(short8*)(xl + base) = l.s;
}

// =================== weight concat / transpose -> hi/lo bf16 planes ===================
// Wh/Wl [896][1024]: rows 0-447 Wskew^T, 448-575 Wk^T, 576-703 Wv^T, 704-831 Wq^T, 832-847 Wbeta^T, 848-895 zero
__global__ __launch_bounds__(256) void concat_kernel(
    const float* __restrict__ Wskew, const float* __restrict__ Wk, const float* __restrict__ Wv,
    const float* __restrict__ Wq, const float* __restrict__ Wbeta, const float* __restrict__ Wo,
    u16* __restrict__ Wh, u16* __restrict__ Wl, u16* __restrict__ WoT)
{
  int idx = blockIdx.x*256 + threadIdx.x;
  if (idx < 896*1024){
    int n = idx >> 10, kk = idx & 1023;
    float v;
    if (n < 448)      v = Wskew[kk*448 + n];
    else if (n < 576) v = Wk[kk*128 + (n-448)];
    else if (n < 704) v = Wv[kk*128 + (n-576)];
    else if (n < 832) v = Wq[kk*128 + (n-704)];
    else if (n < 848) v = Wbeta[kk*16 + (n-832)];
    else              v = 0.f;
    u16 h = f2bf(v);
    Wh[idx] = h;
    Wl[idx] = f2bf(v - bf2f(h));
  } else {
    int r = idx - 896*1024;
    int n = r >> 7, kk = r & 127;
    WoT[r] = f2bf(Wo[kk*1024 + n]);
  }
}

// =================== 4-plane split-bf16 MFMA GEMM + epilogue ===================
// C ~= Ah*Bh + Ah*Bl + Al*Bh (fp32-class). Lane-linear LDS staging (conflict-free).
__global__ __launch_bounds__(256) void gemm_split_kernel(
    const u16* __restrict__ Ah, const u16* __restrict__ Al,
    const u16* __restrict__ Bh, const u16* __restrict__ Bl,
    float* __restrict__ C, const float* __restrict__ bias, int M, int N, int K, int ldc)
{
  __shared__ u16 lAh[128*32]; __shared__ u16 lAl[128*32];
  __shared__ u16 lBh[128*32]; __shared__ u16 lBl[128*32];
  const int tid = threadIdx.x;
  const int wave = tid >> 6;
  const int lane = tid & 63;
  const int quad = lane >> 4, l15 = lane & 15;
  const int m0 = blockIdx.x * 128, n0 = blockIdx.y * 128;
  const int wm = (wave >> 1) * 64, wn = (wave & 1) * 64;
  const int r0 = tid >> 2;              // 0..63
  const int c0 = (tid & 3) * 8;         // 0,8,16,24
  const size_t offA0 = (size_t)(m0 + r0)*K + c0, offA1 = offA0 + (size_t)64*K;
  const size_t offB0 = (size_t)(n0 + r0)*K + c0, offB1 = offB0 + (size_t)64*K;
  const int l0 = r0*32 + c0, l1 = l0 + 64*32;   // lane-linear: byte addr = tid*16

  f32x4 acc[4][4] = {};
  for (int kb = 0; kb < K; kb += 32){
    short8 vah0 = *(const short8*)(Ah + offA0 + kb), vah1 = *(const short8*)(Ah + offA1 + kb);
    short8 val0 = *(const short8*)(Al + offA0 + kb), val1 = *(const short8*)(Al + offA1 + kb);
    short8 vbh0 = *(const short8*)(Bh + offB0 + kb), vbh1 = *(const short8*)(Bh + offB1 + kb);
    short8 vbl0 = *(const short8*)(Bl + offB0 + kb), vbl1 = *(const short8*)(Bl + offB1 + kb);
    __syncthreads();
    *(short8*)&lAh[l0] = vah0;  *(short8*)&lAh[l1] = vah1;
    *(short8*)&lAl[l0] = val0;  *(short8*)&lAl[l1] = val1;
    *(short8*)&lBh[l0] = vbh0;  *(short8*)&lBh[l1] = vbh1;
    *(short8*)&lBl[l0] = vbl0;  *(short8*)&lBl[l1] = vbl1;
    __syncthreads();
    short8 afh[4], afl[4], bfh[4], bfl[4];
    #pragma unroll
    for (int mi=0;mi<4;mi++){
      afh[mi] = *(const short8*)&lAh[(wm + mi*16 + l15)*32 + quad*8];
      afl[mi] = *(const short8*)&lAl[(wm + mi*16 + l15)*32 + quad*8];
    }
    #pragma unroll
    for (int ni=0;ni<4;ni++){
      bfh[ni] = *(const short8*)&lBh[(wn + ni*16 + l15)*32 + quad*8];
      bfl[ni] = *(const short8*)&lBl[(wn + ni*16 + l15)*32 + quad*8];
    }
    #pragma unroll
    for (int mi=0;mi<4;mi++)
      #pragma unroll
      for (int ni=0;ni<4;ni++){
        acc[mi][ni] = __builtin_amdgcn_mfma_f32_16x16x32_bf16(afh[mi], bfh[ni], acc[mi][ni], 0,0,0);
        acc[mi][ni] = __builtin_amdgcn_mfma_f32_16x16x32_bf16(afh[mi], bfl[ni], acc[mi][ni], 0,0,0);
        acc[mi][ni] = __builtin_amdgcn_mfma_f32_16x16x32_bf16(afl[mi], bfh[ni], acc[mi][ni], 0,0,0);
      }
  }
  #pragma unroll
  for (int mi=0;mi<4;mi++){
    #pragma unroll
    for (int ni=0;ni<4;ni++){
      const int col = n0 + wn + ni*16 + l15;
      const int rb_ = m0 + wm + mi*16 + quad*4;
      #pragma unroll
      for (int r=0;r<4;r++){
        float v = acc[mi][ni][r];
        const int row = rb_ + r;
        if (col < 448) v = 0.5f * tanhf(v);
        else if (col >= 832 && col < 848) v = 1.f/(1.f + expf(-(v + bias[col-832])));
        C[(size_t)row*ldc + col] = v;
      }
    }
  }
}

// =================== plain bf16 MFMA GEMM: bf16 A/Bt -> fp32 C ===================
__global__ __launch_bounds__(256) void gemm_bf16_kernel(
    const u16* __restrict__ A, const u16* __restrict__ Bt, float* __restrict__ C,
    int M, int N, int K, int ldc)
{
  __shared__ u16 ldsA[128*32];
  __shared__ u16 ldsB[128*32];
  const int tid = threadIdx.x;
  const int wave = tid >> 6;
  const int lane = tid & 63;
  const int quad = lane >> 4, l15 = lane & 15;
  const int m0 = blockIdx.x * 128, n0 = blockIdx.y * 128;
  const int wm = (wave >> 1) * 64, wn = (wave & 1) * 64;
  const int r0 = tid >> 2;
  const int c0 = (tid & 3) * 8;
  const size_t offA0 = (size_t)(m0 + r0)*K + c0, offA1 = offA0 + (size_t)64*K;
  const size_t offB0 = (size_t)(n0 + r0)*K + c0, offB1 = offB0 + (size_t)64*K;
  const int l0 = r0*32 + c0, l1 = l0 + 64*32;

  f32x4 acc[4][4] = {};
  for (int kb = 0; kb < K; kb += 32){
    short8 a0 = *(const short8*)(A + offA0 + kb), a1 = *(const short8*)(A + offA1 + kb);
    short8 b0 = *(const short8*)(Bt + offB0 + kb), b1 = *(const short8*)(Bt + offB1 + kb);
    __syncthreads();
    *(short8*)&ldsA[l0] = a0;  *(short8*)&ldsA[l1] = a1;
    *(short8*)&ldsB[l0] = b0;  *(short8*)&ldsB[l1] = b1;
    __syncthreads();
    short8 af[4], bf8[4];
    #pragma unroll
    for (int mi=0;mi<4;mi++) af[mi] = *(const short8*)&ldsA[(wm + mi*16 + l15)*32 + quad*8];
    #pragma unroll
    for (int ni=0;ni<4;ni++) bf8[ni] = *(const short8*)&ldsB[(wn + ni*16 + l15)*32 + quad*8];
    #pragma unroll
    for (int mi=0;mi<4;mi++)
      #pragma unroll
      for (int ni=0;ni<4;ni++)
        acc[mi][ni] = __builtin_amdgcn_mfma_f32_16x16x32_bf16(af[mi], bf8[ni], acc[mi][ni], 0,0,0);
  }
  #pragma unroll
  for (int mi=0;mi<4;mi++)
    #pragma unroll
    for (int ni=0;ni<4;ni++){
      const int col = n0 + wn + ni*16 + l15;
      const int rb_ = m0 + wm + mi*16 + quad*4;
      #pragma unroll
      for (int r=0;r<4;r++)
        C[(size_t)(rb_ + r)*ldc + col] = acc[mi][ni][r];
    }
}

// =================== expm of skew (2 lanes per matrix) ===================
__device__ constexpr int TRI_I[28] = {0,0,0,0,0,0,0, 1,1,1,1,1,1, 2,2,2,2,2, 3,3,3,3, 4,4,4, 5,5, 6};
__device__ constexpr int TRI_J[28] = {1,2,3,4,5,6,7, 2,3,4,5,6,7, 3,4,5,6,7, 4,5,6,7, 5,6,7, 6,7, 7};

DEV void pair_matmul(const float XA[4][4], const float XB[4][4], const float Mm[4][8], float Tm[4][8]){
  float Yo[4][8];
  #pragma unroll
  for (int r=0;r<4;r++)
    #pragma unroll
    for (int jj=0;jj<8;jj++) Yo[r][jj] = __shfl_xor(Mm[r][jj], 1);
  #pragma unroll
  for (int i=0;i<4;i++)
    #pragma unroll
    for (int jj=0;jj<8;jj++){
      float acc = 0.f;
      #pragma unroll
      for (int r=0;r<4;r++){ acc = fmaf(XA[i][r], Mm[r][jj], acc); acc = fmaf(XB[i][r], Yo[r][jj], acc); }
      Tm[i][jj] = acc;
    }
}

__global__ __launch_bounds__(256) void expm_kernel(const float* __restrict__ proj, float* __restrict__ O)
{
  const int tid = blockIdx.x*256 + threadIdx.x;
  const int pid = tid >> 1;     // matrix id [0, 262144)
  const int p = tid & 1;        // half: rows 4p..4p+3
  const int row = pid >> 4, h = pid & 15;
  const float* sk = proj + (size_t)row*896 + h*28;

  float Bm[4][8];
  #pragma unroll
  for (int i=0;i<4;i++)
    #pragma unroll
    for (int jj=0;jj<8;jj++) Bm[i][jj] = 0.f;
  #pragma unroll
  for (int c=0;c<28;c++){
    const int ti = TRI_I[c], tj = TRI_J[c];
    float v = sk[c] * 0.0625f;      // A/16 (scaling-and-squaring s=4)
    if (p==0){
      if (ti < 4) Bm[ti][tj] = v;
      if (tj < 4) Bm[tj][ti] = -v;
    } else {
      if (ti >= 4) Bm[ti-4][tj] = v;
      if (tj >= 4) Bm[tj-4][ti] = -v;
    }
  }
  float BA[4][4], BB[4][4];
  #pragma unroll
  for (int i=0;i<4;i++)
    #pragma unroll
    for (int r=0;r<4;r++){ float lo=Bm[i][r], hi=Bm[i][4+r]; BA[i][r] = p? hi: lo; BB[i][r] = p? lo: hi; }

  float Mm[4][8], Tm[4][8];
  #pragma unroll
  for (int i=0;i<4;i++)
    #pragma unroll
    for (int jj=0;jj<8;jj++) Mm[i][jj] = Bm[i][jj]*(1.f/6.f) + (((4*p+i)==jj)?1.f:0.f);
  const float coef[5] = {0.2f, 0.25f, 1.f/3.f, 0.5f, 1.f};
  #pragma unroll
  for (int st=0; st<5; st++){
    pair_matmul(BA, BB, Mm, Tm);
    #pragma unroll
    for (int i=0;i<4;i++)
      #pragma unroll
      for (int jj=0;jj<8;jj++) Mm[i][jj] = Tm[i][jj]*coef[st] + (((4*p+i)==jj)?1.f:0.f);
  }
  #pragma unroll
  for (int sq=0; sq<4; sq++){
    float MA[4][4], MB[4][4];
    #pragma unroll
    for (int i=0;i<4;i++)
      #pragma unroll
      for (int r=0;r<4;r++){ float lo=Mm[i][r], hi=Mm[i][4+r]; MA[i][r] = p? hi: lo; MB[i][r] = p? lo: hi; }
    pair_matmul(MA, MB, Mm, Tm);
    #pragma unroll
    for (int i=0;i<4;i++)
      #pragma unroll
      for (int jj=0;jj<8;jj++) Mm[i][jj] = Tm[i][jj];
  }
  const int b_ = row >> 12, t_ = row & 4095;
  const size_t obase = (((size_t)(b_*16 + h))*4096 + (size_t)t_)*64;
  #pragma unroll
  for (int i=0;i<4;i++){
    f32x4 lo = {Mm[i][0],Mm[i][1],Mm[i][2],Mm[i][3]};
    f32x4 hi = {Mm[i][4],Mm[i][5],Mm[i][6],Mm[i][7]};
    *(f32x4*)(O + obase + (size_t)(4*p+i)*8)     = lo;
    *(f32x4*)(O + obase + (size_t)(4*p+i)*8 + 4) = hi;
  }
}

// helpers: 8x8 matvec with 16 f32x4 regs
DEV void load16(const float* p, f32x4* M){
  #pragma unroll
  for (int q=0;q<16;q++) M[q] = *(const f32x4*)(p + 4*q);
}
DEV void rm_matvec8(const f32x4* M16, const float* x, float* res){
  #pragma unroll
  for (int i=0;i<8;i++){
    float acc = 0.f;
    #pragma unroll
    for (int a=0;a<8;a++) acc = fmaf(M16[2*i + (a>>2)][a&3], x[a], acc);
    res[i] = acc;
  }
}
DEV void cm_matvec8(const f32x4* M16, const float* x, float* res){
  #pragma unroll
  for (int i=0;i<8;i++){
    float acc = 0.f;
    #pragma unroll
    for (int a=0;a<8;a++) acc = fmaf(M16[2*a + (i>>2)][i&3], x[a], acc);
    res[i] = acc;
  }
}

// =================== C1: local prefix products within 64-step chunks ===================
__global__ __launch_bounds__(256) void chunkpfx_kernel(float* __restrict__ OR)
{
  int tid = blockIdx.x*256 + threadIdx.x;   // 32768 = 4096 tasks * 8 lanes
  int task = tid >> 3, j = tid & 7;
  int s = task >> 6, c = task & 63;
  float P[8], Pn[8];
  #pragma unroll
  for (int a=0;a<8;a++) P[a] = (a==j) ? 1.f : 0.f;
  float* base = OR + ((size_t)s*4096 + (size_t)c*64)*64;
  for (int tt=0; tt<64; tt++){
    float* slot = base + (size_t)tt*64;
    f32x4 Oc[16];
    load16(slot, Oc);              // O_t row-major
    rm_matvec8(Oc, P, Pn);         // P <- O_t * P
    #pragma unroll
    for (int a=0;a<8;a++) P[a] = Pn[a];
    f32x4 s0 = {P[0],P[1],P[2],P[3]}, s1 = {P[4],P[5],P[6],P[7]};
    *(f32x4*)(slot + j*8)     = s0;   // store col-major (same-wave: loads precede stores)
    *(f32x4*)(slot + j*8 + 4) = s1;
  }
}

// =================== C2: scan of chunk products -> Rbase_c ===================
__global__ __launch_bounds__(256) void chunkscan_kernel(const float* __restrict__ OR, float* __restrict__ Rbase)
{
  int tid = blockIdx.x*256 + threadIdx.x;   // 512 = 64 seqs * 8 lanes
  int s = tid >> 3, j = tid & 7;
  float Rb[8], Rn[8];
  #pragma unroll
  for (int a=0;a<8;a++) Rb[a] = (a==j) ? 1.f : 0.f;
  for (int c=0;c<64;c++){
    float* dst = Rbase + ((size_t)s*64 + c)*64 + j*8;
    f32x4 s0 = {Rb[0],Rb[1],Rb[2],Rb[3]}, s1 = {Rb[4],Rb[5],Rb[6],Rb[7]};
    *(f32x4*)(dst) = s0; *(f32x4*)(dst+4) = s1;     // col-major Rbase_c
    if (c < 63){
      const float* qs = OR + ((size_t)s*4096 + (size_t)(c*64+63))*64;  // Q_c col-major
      f32x4 Q[16];
      load16(qs, Q);
      cm_matvec8(Q, Rb, Rn);       // Rb <- Q_c * Rb
      #pragma unroll
      for (int a=0;a<8;a++) Rb[a] = Rn[a];
    }
  }
}

// =================== C3: compose R_t, normalize k, rotate k/v/q ===================
// scanin aliased into proj's dead skew slots: scanin(s,t) = proj + row*896 + h*28
__global__ __launch_bounds__(256) void rotate_kvq_kernel(float* __restrict__ OR, const float* __restrict__ Rbase,
    float* __restrict__ proj)
{
  int tid = blockIdx.x*256 + threadIdx.x;   // 262144
  int s = tid >> 12, t = tid & 4095;
  int c = t >> 6;
  int b = s >> 4, h = s & 15;
  int row = b*4096 + t;
  float* slot = OR + ((size_t)s*4096 + t)*64;
  f32x4 P4[16];
  load16(slot, P4);                          // P_c(t), col-major
  float* pr = proj + (size_t)row*896;
  float k[8], v[8], q[8];
  { f32x4 a = *(const f32x4*)(pr+448+h*8), b2 = *(const f32x4*)(pr+452+h*8);
    #pragma unroll
    for (int i=0;i<4;i++){ k[i]=a[i]; k[4+i]=b2[i]; } }
  { f32x4 a = *(const f32x4*)(pr+576+h*8), b2 = *(const f32x4*)(pr+580+h*8);
    #pragma unroll
    for (int i=0;i<4;i++){ v[i]=a[i]; v[4+i]=b2[i]; } }
  { f32x4 a = *(const f32x4*)(pr+704+h*8), b2 = *(const f32x4*)(pr+708+h*8);
    #pragma unroll
    for (int i=0;i<4;i++){ q[i]=a[i]; q[4+i]=b2[i]; } }
  float nn = 0.f;
  #pragma unroll
  for (int i=0;i<8;i++) nn = fmaf(k[i],k[i],nn);
  float inv = 1.f / fmaxf(sqrtf(nn), 1e-6f);
  #pragma unroll
  for (int i=0;i<8;i++) k[i] *= inv;

  const float* rb = Rbase + ((size_t)s*64 + c)*64;
  float kt[8], vt[8], qt[8];
  #pragma unroll
  for (int j=0;j<8;j++){
    float rbv[8];
    { f32x4 a = *(const f32x4*)(rb + j*8), b2 = *(const f32x4*)(rb + j*8 + 4);
      #pragma unroll
      for (int i=0;i<4;i++){ rbv[i]=a[i]; rbv[4+i]=b2[i]; } }
    float Rc[8];
    cm_matvec8(P4, rbv, Rc);        // column j of R_t = P * Rbase[:,j]
    f32x4 s0 = {Rc[0],Rc[1],Rc[2],Rc[3]}, s1 = {Rc[4],Rc[5],Rc[6],Rc[7]};
    *(f32x4*)(slot + j*8) = s0; *(f32x4*)(slot + j*8 + 4) = s1;   // R_t col-major (in place)
    float a0=0.f, a1=0.f, a2=0.f;
    #pragma unroll
    for (int i=0;i<8;i++){ a0 = fmaf(Rc[i],k[i],a0); a1 = fmaf(Rc[i],v[i],a1); a2 = fmaf(Rc[i],q[i],a2); }
    kt[j]=a0; vt[j]=a1; qt[j]=a2;
  }
  float beta = pr[832+h];
  float qk = 0.f;
  #pragma unroll
  for (int j=0;j<8;j++) qk = fmaf(kt[j], qt[j], qk);
  float* sip = pr + h*28;     // dead skew slot of this (row,h); writes <448, reads >=448
  f32x4 w0={kt[0],kt[1],kt[2],kt[3]}, w1={kt[4],kt[5],kt[6],kt[7]};
  f32x4 w2={vt[0],vt[1],vt[2],vt[3]}, w3={vt[4],vt[5],vt[6],vt[7]};
  f32x4 w4={qt[0],qt[1],qt[2],qt[3]}, w5={qt[4],qt[5],qt[6],qt[7]};
  f32x4 w6={beta, qk, 0.f, 0.f};
  *(f32x4*)(sip)=w0; *(f32x4*)(sip+4)=w1; *(f32x4*)(sip+8)=w2; *(f32x4*)(sip+12)=w3;
  *(f32x4*)(sip+16)=w4; *(f32x4*)(sip+20)=w5; *(f32x4*)(sip+24)=w6;
}

// =================== D: chunk-parallel delta scan ===================
__global__ __launch_bounds__(256) void scan_pass1_kernel(const float* __restrict__ proj,
    float* __restrict__ Mbuf, float* __restrict__ wbuf)
{
  int tid = blockIdx.x*256 + threadIdx.x;   // 32768 = 4096 tasks * 8 lanes
  int task = tid >> 3, j = tid & 7;         // task = s*64 + c
  int s = task >> 6, c = task & 63;
  int b = s >> 4, h = s & 15;
  const float* rec = proj + ((size_t)b*4096 + (size_t)c*64)*896 + h*28;
  float m[8], w[8];
  #pragma unroll
  for (int i=0;i<8;i++){ m[i] = (i==j)?1.f:0.f; w[i] = 0.f; }
  for (int tt=0; tt<64; tt++){
    const float* p = rec + (size_t)tt*896;
    f32x4 k0 = *(const f32x4*)(p), k1 = *(const f32x4*)(p+4);
    float vt = p[8+j];
    float beta = p[24];
    float s1, s2;
    s1 = ((k0[0]*m[0] + k0[1]*m[1]) + (k0[2]*m[2] + k0[3]*m[3]))
       + ((k1[0]*m[4] + k1[1]*m[5]) + (k1[2]*m[6] + k1[3]*m[7]));
    s2 = ((k0[0]*w[0] + k0[1]*w[1]) + (k0[2]*w[2] + k0[3]*w[3]))
       + ((k1[0]*w[4] + k1[1]*w[5]) + (k1[2]*w[6] + k1[3]*w[7]));
    float c1 = -beta*s1, c2 = beta*(vt - s2);
    #pragma unroll
    for (int i=0;i<4;i++){ m[i] = fmaf(k0[i], c1, m[i]); m[4+i] = fmaf(k1[i], c1, m[4+i]); }
    #pragma unroll
    for (int i=0;i<4;i++){ w[i] = fmaf(k0[i], c2, w[i]); w[4+i] = fmaf(k1[i], c2, w[4+i]); }
  }
  float* md = Mbuf + (size_t)task*64 + j*8;
  float* wd = wbuf + (size_t)task*64 + j*8;
  f32x4 m0={m[0],m[1],m[2],m[3]}, m1={m[4],m[5],m[6],m[7]};
  f32x4 w0={w[0],w[1],w[2],w[3]}, w1={w[4],w[5],w[6],w[7]};
  *(f32x4*)(md) = m0; *(f32x4*)(md+4) = m1;
  *(f32x4*)(wd) = w0; *(f32x4*)(wd+4) = w1;
}

__global__ __launch_bounds__(64) void scan_mid_kernel(const float* __restrict__ Mbuf,
    const float* __restrict__ wbuf, float* __restrict__ dstart)
{
  int tid = blockIdx.x*64 + threadIdx.x;    // 512 = 64 seqs * 8 lanes
  int s = tid >> 3, j = tid & 7;
  float d[8];
  #pragma unroll
  for (int i=0;i<8;i++) d[i] = 0.f;
  size_t base = (size_t)s*64*64;
  f32x4 M[16]; load16(Mbuf + base, M);
  f32x4 wv0 = *(const f32x4*)(wbuf + base + j*8), wv1 = *(const f32x4*)(wbuf + base + j*8 + 4);
  for (int c=0; c<64; c++){
    float* dd = dstart + base + (size_t)c*64 + j*8;
    f32x4 s0 = {d[0],d[1],d[2],d[3]}, s1 = {d[4],d[5],d[6],d[7]};
    *(f32x4*)(dd) = s0; *(f32x4*)(dd+4) = s1;
    float dn[8];
    cm_matvec8(M, d, dn);
    #pragma unroll
    for (int i=0;i<4;i++){ d[i] = dn[i] + wv0[i]; d[4+i] = dn[4+i] + wv1[i]; }
    if (c < 63){
      size_t nb = base + (size_t)(c+1)*64;
      load16(Mbuf + nb, M);
      wv0 = *(const f32x4*)(wbuf + nb + j*8); wv1 = *(const f32x4*)(wbuf + nb + j*8 + 4);
    }
  }
}

__global__ __launch_bounds__(256) void scan_pass2_kernel(const float* __restrict__ proj,
    const float* __restrict__ dstart, float* __restrict__ oo)
{
  int tid = blockIdx.x*256 + threadIdx.x;   // 32768
  int task = tid >> 3, j = tid & 7;
  int s = task >> 6, c = task & 63;
  int b = s >> 4, h = s & 15;
  const float* rec = proj + ((size_t)b*4096 + (size_t)c*64)*896 + h*28;
  float* op = oo + (((size_t)s*4096 + (size_t)c*64)*8) + j;
  float d[8];
  { const float* ds = dstart + (size_t)task*64 + j*8;
    f32x4 a = *(const f32x4*)(ds), b2 = *(const f32x4*)(ds+4);
    #pragma unroll
    for (int i=0;i<4;i++){ d[i]=a[i]; d[4+i]=b2[i]; } }
  for (int tt=0; tt<64; tt++){
    const float* p = rec + (size_t)tt*896;
    f32x4 k0 = *(const f32x4*)(p),    k1 = *(const f32x4*)(p+4);
    f32x4 q0 = *(const f32x4*)(p+16), q1 = *(const f32x4*)(p+20);
    f32x4 mb = *(const f32x4*)(p+24);           // [beta, qk, -, -]
    float vt = p[8+j];
    float kd, qd;
    kd = ((k0[0]*d[0] + k0[1]*d[1]) + (k0[2]*d[2] + k0[3]*d[3]))
       + ((k1[0]*d[4] + k1[1]*d[5]) + (k1[2]*d[6] + k1[3]*d[7]));
    qd = ((q0[0]*d[0] + q0[1]*d[1]) + (q0[2]*d[2] + q0[3]*d[3]))
       + ((q1[0]*d[4] + q1[1]*d[5]) + (q1[2]*d[6] + q1[3]*d[7]));
    float w_ = mb[0] * (vt - kd);
    #pragma unroll
    for (int i=0;i<4;i++){ d[i] = fmaf(k0[i], w_, d[i]); d[4+i] = fmaf(k1[i], w_, d[4+i]); }
    op[(size_t)tt*8] = fmaf(mb[1], w_, qd);
  }
}

// =================== E: rotate outputs back: o = R_t * o~, write bf16 for out-GEMM ===================
__global__ __launch_bounds__(256) void rotout_kernel(const float* __restrict__ OR, const float* __restrict__ oo,
                                                     u16* __restrict__ obf)
{
  int tid = blockIdx.x*256 + threadIdx.x;   // 262144
  int s = tid >> 12, t = tid & 4095;
  int b = s >> 4, h = s & 15;
  int row = b*4096 + t;
  const float* slot = OR + ((size_t)s*4096 + t)*64;
  f32x4 R4[16];
  load16(slot, R4);
  float u[8];
  { const float* up = oo + ((size_t)s*4096 + t)*8;
    f32x4 a = *(const f32x4*)(up), b2 = *(const f32x4*)(up+4);
    #pragma unroll
    for (int i=0;i<4;i++){ u[i]=a[i]; u[4+i]=b2[i]; } }
  float o[8];
  cm_matvec8(R4, u, o);
  u32 p0 = (u32)f2bf(o[0]) | ((u32)f2bf(o[1])<<16);
  u32 p1 = (u32)f2bf(o[2]) | ((u32)f2bf(o[3])<<16);
  u32 p2 = (u32)f2bf(o[4]) | ((u32)f2bf(o[5])<<16);
  u32 p3 = (u32)f2bf(o[6]) | ((u32)f2bf(o[7])<<16);
  u32x4 pk = {p0,p1,p2,p3};
  *(u32x4*)(void*)(obf + (size_t)row*128 + h*8) = pk;
}

// =================== launch ===================
extern "C" void kernel_launch(void* const* d_in, const int* in_sizes, int n_in,
                              void* d_out, int out_size, void* d_ws, size_t ws_size,
                              hipStream_t stream)
{
  const float* x     = (const float*)d_in[0];
  const float* Wskew = (const float*)d_in[1];
  const float* Wk    = (const float*)d_in[2];
  const float* Wv    = (const float*)d_in[3];
  const float* Wq    = (const float*)d_in[4];
  const float* Wbeta = (const float*)d_in[5];
  const float* bbeta = (const float*)d_in[6];
  const float* Wo    = (const float*)d_in[7];

  char* w = (char*)d_ws; size_t off = 0;
  auto alloc = [&](size_t bytes)->void*{ void* p = w + off; off += (bytes + 255) & ~(size_t)255; return p; };
  u16*   Wh     = (u16*)  alloc((size_t)896*1024*2);
  u16*   Wl     = (u16*)  alloc((size_t)896*1024*2);
  u16*   WoT    = (u16*)  alloc((size_t)1024*128*2);
  float* proj   = (float*)alloc((size_t)16384*896*4);
  float* OR     = (float*)alloc((size_t)262144*64*4);
  float* Rbase  = (float*)alloc((size_t)64*64*64*4);
  float* oo     = (float*)alloc((size_t)262144*8*4);
  float* Mbuf   = (float*)alloc((size_t)4096*64*4);
  float* wbuf   = (float*)alloc((size_t)4096*64*4);
  float* dstart = (float*)alloc((size_t)4096*64*4);
  // aliases: xh/xl live only until gemm_split; OR is written first by expm (after)
  u16*   xh     = (u16*)OR;                       // 32 MB
  u16*   xl     = xh + (size_t)16384*1024;        // 32 MB  (OR region is 64 MB)
  u16*   obf    = (u16*)proj;   // proj fully dead after scan pass2; 4MB << 56MB

  hipLaunchKernelGGL(splitx_kernel, dim3(8192), dim3(256), 0, stream, x, xh, xl);
  hipLaunchKernelGGL(concat_kernel, dim3(4096), dim3(256), 0, stream,
                     Wskew, Wk, Wv, Wq, Wbeta, Wo, Wh, Wl, WoT);
  hipLaunchKernelGGL(gemm_split_kernel, dim3(128,7), dim3(256), 0, stream,
                     xh, xl, Wh, Wl, proj, bbeta, 16384, 896, 1024, 896);
  hipLaunchKernelGGL(expm_kernel, dim3(2048), dim3(256), 0, stream, proj, OR);
  hipLaunchKernelGGL(chunkpfx_kernel, dim3(128), dim3(256), 0, stream, OR);
  hipLaunchKernelGGL(chunkscan_kernel, dim3(2), dim3(256), 0, stream, OR, Rbase);
  hipLaunchKernelGGL(rotate_kvq_kernel, dim3(1024), dim3(256), 0, stream, OR, Rbase, proj);
  hipLaunchKernelGGL(scan_pass1_kernel, dim3(128), dim3(256), 0, stream, proj, Mbuf, wbuf);
  hipLaunchKernelGGL(scan_mid_kernel, dim3(8), dim3(64), 0, stream, Mbuf, wbuf, dstart);
  hipLaunchKernelGGL(scan_pass2_kernel, dim3(128), dim3(256), 0, stream, proj, dstart, oo);
  hipLaunchKernelGGL(rotout_kernel, dim3(1024), dim3(256), 0, stream, OR, oo, obf);
  hipLaunchKernelGGL(gemm_bf16_kernel, dim3(128,8), dim3(256), 0, stream,
                     obf, WoT, (float*)d_out, 16384, 1024, 128, 1024);
}